// Round 1
// 2818.587 us; speedup vs baseline: 1.0983x; 1.0983x over previous
//
#include <hip/hip_runtime.h>
#include <math.h>

typedef __attribute__((ext_vector_type(8))) short bf16x8;
typedef __attribute__((ext_vector_type(4))) float f32x4;

#define BB 64
#define TT 2048
#define RR 256
#define BLK 24
#define NTHR 512
#define HB_PAD 776   // 768 + 8: rows 16B-aligned, stride 388 dw = 4 mod 32 -> 2-way (free)
#define HW_PAD 264   // 256 + 8: same properties

__device__ __forceinline__ unsigned short f2bf(float f) {
    unsigned u = __float_as_uint(f);
    return (unsigned short)((u + 0x7FFFu + ((u >> 16) & 1u)) >> 16);  // RNE
}
__device__ __forceinline__ float bf2f(unsigned short h) {
    return __uint_as_float(((unsigned)h) << 16);
}
// Branch-free tanh: 1 - 2/(1+e^{2x}). v_exp + v_rcp, ~1e-7 abs err, saturates
// correctly (x->+inf: e=inf -> 1; x->-inf: e=0 -> -1). Replaces branchy ocml tanhf
// on the serial path.
__device__ __forceinline__ float fast_tanh(float x) {
    float e = __expf(2.0f * x);
    return 1.0f - 2.0f * __builtin_amdgcn_rcpf(1.0f + e);
}

// ---- Pre-pass: pack tw[tap]*W_fb[tap] into MFMA B-fragment order (bf16) ----
// Layout: chunk c = (tap*8 + kt)*16 + nt; element = c*512 + lane*8 (ushorts).
// Fragment: lane l holds B[k = 32*kt + 8*(l>>4) + j][n = 16*nt + (l&15)], j=0..7.
__global__ void pack_weights(const float* __restrict__ W_fb,
                             const float* __restrict__ tapw,
                             unsigned short* __restrict__ bp) {
    int gid = blockIdx.x * 256 + threadIdx.x;      // 40960 threads
    int l = gid & 63, c = gid >> 6;                // c: 0..639
    int tap = c >> 7;
    int rem = c & 127;
    int kt = rem >> 4, nt = rem & 15;

    float v0 = tapw[0], v1 = tapw[1], v2 = tapw[2], v3 = tapw[3], v4 = tapw[4];
    float mx = fmaxf(fmaxf(fmaxf(v0, v1), fmaxf(v2, v3)), v4);
    float e0 = expf(v0 - mx), e1 = expf(v1 - mx), e2 = expf(v2 - mx),
          e3 = expf(v3 - mx), e4 = expf(v4 - mx);
    float inv = 1.0f / (e0 + e1 + e2 + e3 + e4);
    float tws[5] = {e0 * inv, e1 * inv, e2 * inv, e3 * inv, e4 * inv};
    float tw = tws[tap];

    int kbase = 32 * kt + 8 * (l >> 4);
    int n = 16 * nt + (l & 15);
    const float* W = W_fb + tap * 65536;
    unsigned short t[8];
#pragma unroll
    for (int j = 0; j < 8; ++j) t[j] = f2bf(tw * W[(kbase + j) * 256 + n]);
    uint4 o;
    o.x = (unsigned)t[0] | ((unsigned)t[1] << 16);
    o.y = (unsigned)t[2] | ((unsigned)t[3] << 16);
    o.z = (unsigned)t[4] | ((unsigned)t[5] << 16);
    o.w = (unsigned)t[6] | ((unsigned)t[7] << 16);
    *(uint4*)(bp + (size_t)(c * 64 + l) * 8) = o;
}

// ---- Main kernel: one WG per batch, 8 waves; wave w owns s in [32w, 32w+32) ----
// R1 changes vs 3095us baseline:
//  (1) no per-step global stores: h buffered in LDS hob[BLK][RR], flushed per block
//      (removes per-step vmcnt(0) store-drain at __syncthreads)
//  (2) var-split MFMA accumulators: dep-chain depth 16->8 (tap1/tap4), 48->24 (far)
//  (3) fast_tanh on the serial path
//  (4) staging full-unrolled float4 (loads all in flight); tap-24 staged from hob
//      (LDS) instead of global; far-GEMM B-fragments prefetched 1 iter ahead
//  (5) bias + x*W_in folded into Gl writeback (off the serial path)
__global__ __launch_bounds__(NTHR, 1)
void reservoir_mfma(const float* __restrict__ x,
                    const float* __restrict__ W_in,
                    const float* __restrict__ bias,
                    const unsigned short* __restrict__ bp,
                    float* __restrict__ out)
{
    const int b    = blockIdx.x;
    const int tid  = threadIdx.x;
    const int lane = tid & 63;
    const int w    = tid >> 6;
    const int l15  = lane & 15;
    const int quad = lane >> 4;

    __shared__ float xs[TT];                             // 8 KB
    __shared__ unsigned short hwinb[8][2][HW_PAD];       // 8.25 KB: h ring, bf16 hi/lo
    __shared__ unsigned short hbcb[BLK][2][HB_PAD];      // 72.8 KB: far history hi/lo
    __shared__ float Gl[BLK][257];                       // 24.1 KB: far-tap + drive + bias
    __shared__ float hob[BLK][RR];                       // 24 KB: block h output buffer

    for (int i = tid; i < TT; i += NTHR) xs[i] = x[b * TT + i];
    {
        unsigned* hz = (unsigned*)&hwinb[0][0][0];
        for (int i = tid; i < 8 * 2 * HW_PAD / 2; i += NTHR) hz[i] = 0u;
    }

    // Resident B-fragments: tap d=1 (b1) and d=4 (b4).
    const bf16x8* bpv = (const bf16x8*)bp;
    bf16x8 b1[8][2], b4[8][2];
#pragma unroll
    for (int kt = 0; kt < 8; ++kt)
#pragma unroll
        for (int u = 0; u < 2; ++u) {
            int nt = 2 * w + u;
            b1[kt][u] = bpv[((0 * 8 + kt) * 16 + nt) * 64 + lane];
            b4[kt][u] = bpv[((1 * 8 + kt) * 16 + nt) * 64 + lane];
        }

    const int s0g = 32 * w + l15, s1g = s0g + 16;
    const float win0 = W_in[s0g], win1 = W_in[s1g];
    const float bi0 = bias[s0g], bi1 = bias[s1g];
    float hp0 = 0.0f, hp1 = 0.0f;

    const float* outr = out + (size_t)b * TT * RR;
    float*       outw = out + (size_t)b * TT * RR;

    __syncthreads();

    for (int t0 = 0; t0 < TT; t0 += BLK) {
        // ---- stage far history (pre-softmax-scaled W, so pure hi/lo cvt) ----
        // i -> (j, r): row j in [0,24), r in [0,768) step 4. kf = r>>8 selects tap
        // {24, 96, 168}. Each wave covers a single (j, kf) region: no divergence.
        // tap-24 history is exactly the previous block's hob (still resident in LDS).
#pragma unroll
        for (int it = 0; it < 9; ++it) {                  // 9*512 = 4608 = 24*768/4
            int i = it * NTHR + tid;
            int j = i / 192;
            int p = i - j * 192;
            int r = 4 * p;
            int kf = r >> 8, rr = r & 255;
            float4 v = {0.f, 0.f, 0.f, 0.f};
            if (kf == 0) {
                if (t0 > 0) v = *(const float4*)&hob[j][rr];
            } else {
                int dk = (kf == 1) ? 96 : 168;
                int tt = t0 + j - dk;
                if (tt >= 0) v = *(const float4*)(outr + (size_t)tt * RR + rr);
            }
            unsigned short h0 = f2bf(v.x), h1 = f2bf(v.y), h2 = f2bf(v.z), h3 = f2bf(v.w);
            unsigned short q0 = f2bf(v.x - bf2f(h0)), q1 = f2bf(v.y - bf2f(h1)),
                           q2 = f2bf(v.z - bf2f(h2)), q3 = f2bf(v.w - bf2f(h3));
            uint2 H = { (unsigned)h0 | ((unsigned)h1 << 16), (unsigned)h2 | ((unsigned)h3 << 16) };
            uint2 Q = { (unsigned)q0 | ((unsigned)q1 << 16), (unsigned)q2 | ((unsigned)q3 << 16) };
            *(uint2*)&hbcb[j][0][r] = H;
            *(uint2*)&hbcb[j][1][r] = Q;
        }
        __syncthreads();

        // ---- far GEMM: C[24 j][32 s/wave] over K=768, hi+lo A, var-split accs ----
        f32x4 zf = {0.f, 0.f, 0.f, 0.f};
        f32x4 cf00a = zf, cf01a = zf, cf10a = zf, cf11a = zf;
        f32x4 cf00b = zf, cf01b = zf, cf10b = zf, cf11b = zf;
        const int r0a = l15;              // m-tile 0: j = 0..15
        const int r1a = 16 + (l15 & 7);   // m-tile 1: j = 16..23 (dup rows discarded)
        // chunk index for far tap ft: tap = 2+(ft>>3), ktp = ft&7 -> (16+ft)
        bf16x8 nB0 = bpv[((16 + 0) * 16 + 2 * w + 0) * 64 + lane];
        bf16x8 nB1 = bpv[((16 + 0) * 16 + 2 * w + 1) * 64 + lane];
#pragma unroll 1
        for (int ft = 0; ft < 24; ++ft) {
            bf16x8 B0 = nB0, B1 = nB1;
            int nf = (ft < 23) ? ft + 1 : 23;             // prefetch next (dup at end)
            nB0 = bpv[((16 + nf) * 16 + 2 * w + 0) * 64 + lane];
            nB1 = bpv[((16 + nf) * 16 + 2 * w + 1) * 64 + lane];
            int ro = 32 * ft + 8 * quad;
            bf16x8 a00 = *(const bf16x8*)&hbcb[r0a][0][ro];
            bf16x8 a01 = *(const bf16x8*)&hbcb[r0a][1][ro];
            bf16x8 a10 = *(const bf16x8*)&hbcb[r1a][0][ro];
            bf16x8 a11 = *(const bf16x8*)&hbcb[r1a][1][ro];
            cf00a = __builtin_amdgcn_mfma_f32_16x16x32_bf16(a00, B0, cf00a, 0, 0, 0);
            cf01a = __builtin_amdgcn_mfma_f32_16x16x32_bf16(a00, B1, cf01a, 0, 0, 0);
            cf10a = __builtin_amdgcn_mfma_f32_16x16x32_bf16(a10, B0, cf10a, 0, 0, 0);
            cf11a = __builtin_amdgcn_mfma_f32_16x16x32_bf16(a10, B1, cf11a, 0, 0, 0);
            cf00b = __builtin_amdgcn_mfma_f32_16x16x32_bf16(a01, B0, cf00b, 0, 0, 0);
            cf01b = __builtin_amdgcn_mfma_f32_16x16x32_bf16(a01, B1, cf01b, 0, 0, 0);
            cf10b = __builtin_amdgcn_mfma_f32_16x16x32_bf16(a11, B0, cf10b, 0, 0, 0);
            cf11b = __builtin_amdgcn_mfma_f32_16x16x32_bf16(a11, B1, cf11b, 0, 0, 0);
        }
        f32x4 cf00 = cf00a + cf00b, cf01 = cf01a + cf01b;
        f32x4 cf10 = cf10a + cf10b, cf11 = cf11a + cf11b;
        // writeback + fold bias and drive: Gl[j][s] = far[j][s] + bias[s] + x[t0+j]*Win[s]
#pragma unroll
        for (int i = 0; i < 4; ++i) {
            int j0 = 4 * quad + i;
            int tx0 = t0 + j0; float xv0 = xs[tx0 < TT ? tx0 : TT - 1];
            Gl[j0][s0g] = cf00[i] + bi0 + xv0 * win0;
            Gl[j0][s1g] = cf01[i] + bi1 + xv0 * win1;
            int j1 = 16 + 4 * quad + i;
            if (j1 < BLK) {
                int tx1 = t0 + j1; float xv1 = xs[tx1 < TT ? tx1 : TT - 1];
                Gl[j1][s0g] = cf10[i] + bi0 + xv1 * win0;
                Gl[j1][s1g] = cf11[i] + bi1 + xv1 * win1;
            }
        }
        __syncthreads();

        // ---- sequential sub-blocks of 4 steps ----
        const int tend = (t0 + BLK < TT) ? (t0 + BLK) : TT;
#pragma unroll 1
        for (int t4 = t0; t4 < tend; t4 += 4) {
            // tap d=4: M=4 MFMA, var-split accumulators (depth 8 chains)
            f32x4 c40a = zf, c40b = zf, c41a = zf, c41b = zf;
            const int sl = (t4 - 4 + (l15 & 3)) & 7;
#pragma unroll
            for (int kt = 0; kt < 8; ++kt) {
                int ro = 32 * kt + 8 * quad;
                bf16x8 a0 = *(const bf16x8*)&hwinb[sl][0][ro];
                bf16x8 a1 = *(const bf16x8*)&hwinb[sl][1][ro];
                c40a = __builtin_amdgcn_mfma_f32_16x16x32_bf16(a0, b4[kt][0], c40a, 0, 0, 0);
                c41a = __builtin_amdgcn_mfma_f32_16x16x32_bf16(a0, b4[kt][1], c41a, 0, 0, 0);
                c40b = __builtin_amdgcn_mfma_f32_16x16x32_bf16(a1, b4[kt][0], c40b, 0, 0, 0);
                c41b = __builtin_amdgcn_mfma_f32_16x16x32_bf16(a1, b4[kt][1], c41b, 0, 0, 0);
            }
            f32x4 c40 = c40a + c40b, c41 = c41a + c41b;
            // 4 sequential steps; tap d=1 per step (broadcast A), var-split accs
#pragma unroll
            for (int u = 0; u < 4; ++u) {
                const int t = t4 + u;
                const int sp = (t - 1) & 7;
                f32x4 c10a = zf, c10b = zf, c11a = zf, c11b = zf;
#pragma unroll
                for (int kt = 0; kt < 8; ++kt) {
                    int ro = 32 * kt + 8 * quad;
                    bf16x8 a0 = *(const bf16x8*)&hwinb[sp][0][ro];
                    bf16x8 a1 = *(const bf16x8*)&hwinb[sp][1][ro];
                    c10a = __builtin_amdgcn_mfma_f32_16x16x32_bf16(a0, b1[kt][0], c10a, 0, 0, 0);
                    c11a = __builtin_amdgcn_mfma_f32_16x16x32_bf16(a0, b1[kt][1], c11a, 0, 0, 0);
                    c10b = __builtin_amdgcn_mfma_f32_16x16x32_bf16(a1, b1[kt][0], c10b, 0, 0, 0);
                    c11b = __builtin_amdgcn_mfma_f32_16x16x32_bf16(a1, b1[kt][1], c11b, 0, 0, 0);
                }
                // update (valid on lanes 0..15: C row 0 -> component 0)
                int jj = t - t0;
                float f0 = (c10a[0] + c10b[0]) + c40[u] + Gl[jj][s0g];
                float f1 = (c11a[0] + c11b[0]) + c41[u] + Gl[jj][s1g];
                float h0 = 0.9f * hp0 + 0.1f * fast_tanh(f0);
                float h1 = 0.9f * hp1 + 0.1f * fast_tanh(f1);
                hp0 = h0; hp1 = h1;
                const int wsl = t & 7;
                if (lane < 16) {
                    unsigned short hh0 = f2bf(h0), hh1 = f2bf(h1);
                    hwinb[wsl][0][s0g] = hh0;
                    hwinb[wsl][0][s1g] = hh1;
                    hwinb[wsl][1][s0g] = f2bf(h0 - bf2f(hh0));
                    hwinb[wsl][1][s1g] = f2bf(h1 - bf2f(hh1));
                    hob[jj][s0g] = h0;   // LDS only; global store deferred to flush
                    hob[jj][s1g] = h1;
                }
                __syncthreads();
            }
        }

        // ---- flush hob -> out, coalesced float4 (drained at next block's barrier;
        //      earliest global re-read of these rows is 3 blocks later) ----
        {
            const int nf4 = (tend - t0) * (RR / 4);       // 1536, or 512 in last block
            const float4* src = (const float4*)&hob[0][0];
            float4* dst = (float4*)(outw + (size_t)t0 * RR);
#pragma unroll
            for (int it = 0; it < 3; ++it) {
                int idx = it * NTHR + tid;
                if (idx < nf4) dst[idx] = src[idx];
            }
        }
        // no barrier here: next staging reads hob (already visible since last step's
        // __syncthreads) and writes hbcb (quiescent since far GEMM's barrier).
    }
}

extern "C" void kernel_launch(void* const* d_in, const int* in_sizes, int n_in,
                              void* d_out, int out_size, void* d_ws, size_t ws_size,
                              hipStream_t stream) {
    const float* x    = (const float*)d_in[0];   // (64, 2048, 1)
    const float* W_in = (const float*)d_in[1];   // (256, 1)
    const float* W_fb = (const float*)d_in[2];   // (5, 256, 256)
    const float* tapw = (const float*)d_in[3];   // (5,)
    const float* bias = (const float*)d_in[4];   // (256,)
    float* out = (float*)d_out;                  // (64, 2048, 256)
    unsigned short* bp = (unsigned short*)d_ws;  // 640 KB packed bf16 B-fragments

    pack_weights<<<160, 256, 0, stream>>>(W_fb, tapw, bp);
    reservoir_mfma<<<BB, NTHR, 0, stream>>>(x, W_in, bias, bp, out);
}